// Round 12
// baseline (642.569 us; speedup 1.0000x reference)
//
#include <hip/hip_runtime.h>

typedef __attribute__((ext_vector_type(8))) short short8;
typedef __attribute__((ext_vector_type(4))) float f32x4;
typedef __attribute__((ext_vector_type(4))) int int4v;

#define TMASK  ((1u << 18) - 1u)
#define PRIME1 2654435761u
#define PRIME2 805459861u

// floor(16*SCALE^k), numpy SCALE = exp(ln(256)/16) rounds one ulp BELOW sqrt(2)
// -> even-k levels are 2^m - 1. Verified: rounds 7-11 PASS.
__constant__ float c_res[16] = {16.f, 22.f, 31.f, 45.f, 63.f, 90.f, 127.f, 181.f,
                                255.f, 362.f, 511.f, 724.f, 1023.f, 1448.f, 2047.f, 2896.f};

__device__ __forceinline__ unsigned short rne_bf16(float v) {
  unsigned u = __builtin_bit_cast(unsigned, v);
  return (unsigned short)((u + 0x7fffu + ((u >> 16) & 1u)) >> 16);
}
__device__ __forceinline__ float b2f(unsigned short h) {
  unsigned u = (unsigned)h << 16;
  return __builtin_bit_cast(float, u);
}

// one (point, level): 8-corner gather + smoothstep blend (verified body, r11)
__device__ __forceinline__ float2 enc_level(float x0, float x1, float x2, int lvl,
                                            const float* __restrict__ Tb) {
  const float r = c_res[lvl];
  const float xs0 = x0 * r, xs1 = x1 * r, xs2 = x2 * r;   // plain f32 (jax semantics)
  const float f0 = floorf(xs0), f1 = floorf(xs1), f2 = floorf(xs2);
  const float t0 = xs0 - f0, t1 = xs1 - f1, t2 = xs2 - f2;
  const float w0 = t0 * t0 * (3.f - 2.f * t0);
  const float w1v = t1 * t1 * (3.f - 2.f * t1);
  const float w2v = t2 * t2 * (3.f - 2.f * t2);
  const unsigned cx0 = (unsigned)(int)f0;
  const unsigned hy0 = (unsigned)(int)f1 * PRIME1, hy1 = hy0 + PRIME1;
  const unsigned hz0 = (unsigned)(int)f2 * PRIME2, hz1 = hz0 + PRIME2;
  const float2* tab = reinterpret_cast<const float2*>(Tb) + ((size_t)lvl << 18);
  float a0 = 0.f, a1 = 0.f;
  if (!(cx0 & 1u)) {
    const float4* tab4 = reinterpret_cast<const float4*>(tab);
#pragma unroll
    for (int jk = 0; jk < 4; ++jk) {
      const unsigned hb = (cx0 ^ ((jk & 2) ? hy1 : hy0) ^ ((jk & 1) ? hz1 : hz0)) & TMASK;
      const float4 q = tab4[hb >> 1];
      float e0x, e0y, e1x, e1y;
      if (hb & 1) { e0x = q.z; e0y = q.w; e1x = q.x; e1y = q.y; }
      else        { e0x = q.x; e0y = q.y; e1x = q.z; e1y = q.w; }
      const float wy = (jk & 2) ? w1v : 1.f - w1v;
      const float wz = (jk & 1) ? w2v : 1.f - w2v;
      const float wt0 = ((1.f - w0) * wy) * wz;   // exact ((wx*wy)*wz) order
      const float wt1 = (w0 * wy) * wz;
      a0 = fmaf(e0x, wt0, a0); a1 = fmaf(e0y, wt0, a1);
      a0 = fmaf(e1x, wt1, a0); a1 = fmaf(e1y, wt1, a1);
    }
  } else {
#pragma unroll
    for (int c = 0; c < 8; ++c) {
      const unsigned hx = cx0 + (unsigned)((c >> 2) & 1);
      const unsigned hh = (hx ^ ((c & 2) ? hy1 : hy0) ^ ((c & 1) ? hz1 : hz0)) & TMASK;
      const float2 f = tab[hh];
      const float wt = (((c >> 2) & 1) ? w0 : 1.f - w0) *
                       (((c >> 1) & 1) ? w1v : 1.f - w1v) *
                       (((c & 1)) ? w2v : 1.f - w2v);
      a0 = fmaf(f.x, wt, a0);
      a1 = fmaf(f.y, wt, a1);
    }
  }
  return make_float2(a0, a1);
}

// ============ Fused persistent producer-consumer kernel ============
// grid = 512 (2 blocks/CU, all co-resident -> no deadlock). Block b:
//  - encodes levels {g, 15-g} (g=b&7, XCD-pinned for L2 table residency)
//    for point-groups (b>>3) + t*64, t=0..63 -> flags[grp] system atomicAdd
//  - interleaved, consumes its 32 owned MLP chunks c = b + i*512 (ready at
//    t~2i) with non-blocking checks; drains the tail after encode completes.
// encF handoff via system-scope dword stores/loads (coherent point, no L2
// invalidates -> table-hot L2 preserved). Out stores nontemporal.
__global__ __launch_bounds__(256, 2) void fused_pc(
    const float* __restrict__ X, const float* __restrict__ Tb,
    const float* __restrict__ W1, const float* __restrict__ W2,
    unsigned short* __restrict__ encF, int* __restrict__ flags,
    float* __restrict__ Out) {
  __shared__ __align__(16) unsigned char lds[76800];
  __shared__ int ldsflag;
  unsigned short* w1S  = (unsigned short*)lds;             // [4 c8][128 col][8]
  float*          w1x  = (float*)(lds + 8192);             // [3][128]
  float*          xyzS = (float*)(lds + 9728);             // [64][4]
  unsigned short* w2hS = (unsigned short*)(lds + 10752);   // [16 c8][129][8]
  float*          hS   = (float*)(lds + 43776);            // [64][128]
  float*          outS = (float*)(lds + 43776);            // [64][129] overlay

  const int tid = threadIdx.x;
  const int lane = tid & 63, w = tid >> 6;
  const int b = blockIdx.x;
  const int g = b & 7;
  const int bslot = b >> 3;
  const int lvlA = g, lvlB = 15 - g;

  // ---- stage weights (verified r11) ----
  for (int idx = tid; idx < 32 * 128; idx += 256) {
    const int k = idx >> 7, col = idx & 127;
    w1S[((k >> 3) * 128 + col) * 8 + (k & 7)] = rne_bf16(W1[(k + 3) * 128 + col]);
  }
  for (int idx = tid; idx < 3 * 128; idx += 256) w1x[idx] = W1[idx];
  for (int idx = tid; idx < 128 * 129; idx += 256) {
    const int k = idx / 129, col = idx - k * 129;
    w2hS[((k >> 3) * 129 + col) * 8 + (k & 7)] = rne_bf16(W2[idx]);
  }
  __syncthreads();

  int nextI = 0;

  auto mlp_chunk = [&](int chunk) {
    // af: 4 system-scope dword loads (coherent point; no L2 invalidate)
    const size_t base_int = ((size_t)(chunk * 4 + w) * 64 + lane) * 4;
    int4v ai;
#pragma unroll
    for (int e = 0; e < 4; ++e)
      ai[e] = __hip_atomic_load((int*)encF + base_int + e,
                                __ATOMIC_RELAXED, __HIP_MEMORY_SCOPE_SYSTEM);
    const short8 af = __builtin_bit_cast(short8, ai);
    const int row0 = chunk << 6;
    if (tid < 192) xyzS[(tid / 3) * 4 + (tid % 3)] = X[(size_t)row0 * 3 + tid];
    __syncthreads();   // B1

    f32x4 acc1[8];
#pragma unroll
    for (int c = 0; c < 8; ++c) acc1[c] = (f32x4){0.f, 0.f, 0.f, 0.f};
#pragma unroll
    for (int c = 0; c < 8; ++c) {
      const short8 bb = *reinterpret_cast<const short8*>(
          &w1S[((lane >> 4) * 128 + c * 16 + (lane & 15)) * 8]);
      acc1[c] = __builtin_amdgcn_mfma_f32_16x16x32_bf16(af, bb, acc1[c], 0, 0, 0);
    }
#pragma unroll
    for (int r = 0; r < 4; ++r) {
      const int grow = (w << 4) + (lane >> 4) * 4 + r;
      const float xs0 = xyzS[grow * 4 + 0];
      const float xs1 = xyzS[grow * 4 + 1];
      const float xs2 = xyzS[grow * 4 + 2];
#pragma unroll
      for (int c = 0; c < 8; ++c) {
        const int col = c * 16 + (lane & 15);
        float v = acc1[c][r];
        v = fmaf(xs0, w1x[col], v);
        v = fmaf(xs1, w1x[128 + col], v);
        v = fmaf(xs2, w1x[256 + col], v);
        acc1[c][r] = v;
      }
    }
#pragma unroll
    for (int c = 0; c < 8; ++c) {
#pragma unroll
      for (int r = 0; r < 4; ++r) {
        const int row = (w << 4) + (lane >> 4) * 4 + r;
        const int col = c * 16 + (lane & 15);
        const int cc = (col >> 2) ^ (row & 7);
        hS[row * 128 + (cc << 2) + (col & 3)] = fmaxf(acc1[c][r], 0.f);
      }
    }
    __syncthreads();   // B2

    const int arow = (w << 4) + (lane & 15);
    short8 a2h[4], a2l[4];
#pragma unroll
    for (int kc = 0; kc < 4; ++kc) {
      const int c8 = kc * 4 + (lane >> 4);
      const int base = arow * 128;
      const int cc0 = (2 * c8) ^ (arow & 7);
      const int cc1 = (2 * c8 + 1) ^ (arow & 7);
      const f32x4 q0 = *reinterpret_cast<const f32x4*>(&hS[base + (cc0 << 2)]);
      const f32x4 q1 = *reinterpret_cast<const f32x4*>(&hS[base + (cc1 << 2)]);
#pragma unroll
      for (int e = 0; e < 4; ++e) {
        const unsigned short hi = rne_bf16(q0[e]);
        a2h[kc][e] = (short)hi;
        a2l[kc][e] = (short)rne_bf16(q0[e] - b2f(hi));
      }
#pragma unroll
      for (int e = 0; e < 4; ++e) {
        const unsigned short hi = rne_bf16(q1[e]);
        a2h[kc][4 + e] = (short)hi;
        a2l[kc][4 + e] = (short)rne_bf16(q1[e] - b2f(hi));
      }
    }
    __syncthreads();   // B3: h consumed, outS overlay safe

#pragma unroll
    for (int c = 0; c < 9; ++c) {
      f32x4 acc = (f32x4){0.f, 0.f, 0.f, 0.f};
      int bcol = c * 16 + (lane & 15);
      if (bcol > 128) bcol = 128;
#pragma unroll
      for (int kc = 0; kc < 4; ++kc) {
        const int c8 = kc * 4 + (lane >> 4);
        const short8 bh = *reinterpret_cast<const short8*>(&w2hS[(c8 * 129 + bcol) * 8]);
        acc = __builtin_amdgcn_mfma_f32_16x16x32_bf16(a2h[kc], bh, acc, 0, 0, 0);
        acc = __builtin_amdgcn_mfma_f32_16x16x32_bf16(a2l[kc], bh, acc, 0, 0, 0);
      }
      const int col = c * 16 + (lane & 15);
      if (col < 129) {
#pragma unroll
        for (int r = 0; r < 4; ++r) {
          const int lrow = (w << 4) + (lane >> 4) * 4 + r;
          outS[lrow * 129 + col] = acc[r];
        }
      }
    }
    __syncthreads();   // B4

    float* dst = Out + (size_t)row0 * 129;
    const f32x4* src = (const f32x4*)outS;
    for (int i = tid; i < 2064; i += 256)
      __builtin_nontemporal_store(src[i], reinterpret_cast<f32x4*>(dst + 4 * i));
  };

  // ---- main interleaved loop ----
  for (int t = 0; t < 64; ++t) {
    const int grp = bslot + t * 64;           // 0..4095
    {
      const int p = (grp << 8) + tid;
      const float x0 = X[p * 3 + 0];
      const float x1 = X[p * 3 + 1];
      const float x2 = X[p * 3 + 2];
      const int pl = p & 63, chunk = p >> 6;
      const size_t rowbase = ((size_t)(chunk * 4 + (pl >> 4)) * 64 + (pl & 15)) * 8;
#pragma unroll
      for (int li = 0; li < 2; ++li) {
        const int lvl = li ? lvlB : lvlA;
        const float2 a = enc_level(x0, x1, x2, lvl, Tb);
        const int c8 = lvl >> 2;
        const size_t addr_short = rowbase + (size_t)(c8 << 7) + (lvl & 3) * 2;
        const int val = (int)rne_bf16(a.x) | ((int)rne_bf16(a.y) << 16);
        __hip_atomic_store((int*)encF + (addr_short >> 1), val,
                           __ATOMIC_RELAXED, __HIP_MEMORY_SCOPE_SYSTEM);
      }
    }
    __syncthreads();   // drains vmcnt before flag (compiler emits vmcnt(0))
    if (tid == 0)
      __hip_atomic_fetch_add(&flags[grp], 1, __ATOMIC_RELAXED, __HIP_MEMORY_SCOPE_SYSTEM);

    // opportunistic MLP (non-blocking)
    while (nextI < 32) {
      const int c = b + (nextI << 9);
      if (tid == 0)
        ldsflag = __hip_atomic_load(&flags[c >> 2], __ATOMIC_RELAXED,
                                    __HIP_MEMORY_SCOPE_SYSTEM);
      __syncthreads();
      if (ldsflag != 8) break;   // block-uniform
      mlp_chunk(c);
      ++nextI;
    }
  }

  // ---- drain tail (blocking; all encode flags guaranteed to arrive) ----
  while (nextI < 32) {
    const int c = b + (nextI << 9);
    for (;;) {
      if (tid == 0)
        ldsflag = __hip_atomic_load(&flags[c >> 2], __ATOMIC_RELAXED,
                                    __HIP_MEMORY_SCOPE_SYSTEM);
      __syncthreads();
      if (ldsflag == 8) break;
      __builtin_amdgcn_s_sleep(32);
      __syncthreads();
    }
    mlp_chunk(c);
    ++nextI;
  }
}

// ================= Fallback (round-8 fused kernel, verified) =================
__global__ __launch_bounds__(256) void fused_hashmlp(
    const float* __restrict__ X, const float* __restrict__ Tb,
    const float* __restrict__ W1, const float* __restrict__ W2,
    float* __restrict__ Out, int nChunks) {
  __shared__ __align__(16) unsigned char lds[147968];
  unsigned short* w1hS = (unsigned short*)lds;
  unsigned short* w1lS = w1hS + 128 * 64;
  unsigned short* w2hS = (unsigned short*)(lds + 32768);
  unsigned short* w2lS = w2hS + 129 * 128;
  unsigned short* enchS = (unsigned short*)(lds + 98816);
  unsigned short* enclS = enchS + 64 * 64;
  float*          hS    = (float*)(lds + 115200);
  float*          outS  = (float*)(lds + 98816);

  const int tid = threadIdx.x;
  for (int idx = tid; idx < 128 * 64; idx += 256) {
    int k = idx >> 7, col = idx & 127;
    float v = 0.f;
    if (k < 35) { int r = (k < 32) ? (k + 3) : (k - 32); v = W1[r * 128 + col]; }
    unsigned short hi = rne_bf16(v);
    unsigned short lo = rne_bf16(v - b2f(hi));
    int a = col * 64 + (k ^ ((col & 7) << 3));
    w1hS[a] = hi; w1lS[a] = lo;
  }
  for (int idx = tid; idx < 129 * 128; idx += 256) {
    int k = idx / 129, col = idx - k * 129;
    float v = W2[k * 129 + col];
    unsigned short hi = rne_bf16(v);
    unsigned short lo = rne_bf16(v - b2f(hi));
    int a = col * 128 + (k ^ ((col & 7) << 3));
    w2hS[a] = hi; w2lS[a] = lo;
  }
  __syncthreads();

  const int p = tid >> 2, s = tid & 3, lane = tid & 63, w = tid >> 6;
  for (int chunk = blockIdx.x; chunk < nChunks; chunk += gridDim.x) {
    const int row0 = chunk * 64;
    {
      const int gp = row0 + p;
      const float x0 = X[gp * 3 + 0], x1 = X[gp * 3 + 1], x2 = X[gp * 3 + 2];
      short8 pkh, pkl;
#pragma unroll
      for (int li = 0; li < 4; ++li) {
        const int lvl = (s << 2) + li;
        const float2 a = enc_level(x0, x1, x2, lvl, Tb);
        unsigned short h0 = rne_bf16(a.x), h1 = rne_bf16(a.y);
        pkh[li * 2 + 0] = (short)h0; pkh[li * 2 + 1] = (short)h1;
        pkl[li * 2 + 0] = (short)rne_bf16(a.x - b2f(h0));
        pkl[li * 2 + 1] = (short)rne_bf16(a.y - b2f(h1));
      }
      const int coff = (s ^ (p & 7)) << 3;
      *reinterpret_cast<short8*>(&enchS[p * 64 + coff]) = pkh;
      *reinterpret_cast<short8*>(&enclS[p * 64 + coff]) = pkl;
      short8 zh, zl;
#pragma unroll
      for (int e = 0; e < 8; ++e) { zh[e] = 0; zl[e] = 0; }
      if (s == 0) {
        unsigned short hx0 = rne_bf16(x0), hx1 = rne_bf16(x1), hx2 = rne_bf16(x2);
        zh[0] = (short)hx0; zh[1] = (short)hx1; zh[2] = (short)hx2;
        zl[0] = (short)rne_bf16(x0 - b2f(hx0));
        zl[1] = (short)rne_bf16(x1 - b2f(hx1));
        zl[2] = (short)rne_bf16(x2 - b2f(hx2));
      }
      const int coff2 = ((4 + s) ^ (p & 7)) << 3;
      *reinterpret_cast<short8*>(&enchS[p * 64 + coff2]) = zh;
      *reinterpret_cast<short8*>(&enclS[p * 64 + coff2]) = zl;
    }
    __syncthreads();
    f32x4 acc1[8];
#pragma unroll
    for (int c = 0; c < 8; ++c) acc1[c] = (f32x4){0.f, 0.f, 0.f, 0.f};
    {
      const int arow = (w << 4) + (lane & 15);
#pragma unroll
      for (int kc = 0; kc < 2; ++kc) {
        const int c8 = kc * 4 + (lane >> 4);
        const int aoff = arow * 64 + ((c8 ^ (arow & 7)) << 3);
        const short8 ah = *reinterpret_cast<const short8*>(&enchS[aoff]);
        const short8 al = *reinterpret_cast<const short8*>(&enclS[aoff]);
#pragma unroll
        for (int c = 0; c < 8; ++c) {
          const int bcol = c * 16 + (lane & 15);
          const int boff = bcol * 64 + ((c8 ^ (bcol & 7)) << 3);
          const short8 bh = *reinterpret_cast<const short8*>(&w1hS[boff]);
          const short8 bl = *reinterpret_cast<const short8*>(&w1lS[boff]);
          acc1[c] = __builtin_amdgcn_mfma_f32_16x16x32_bf16(ah, bh, acc1[c], 0, 0, 0);
          acc1[c] = __builtin_amdgcn_mfma_f32_16x16x32_bf16(ah, bl, acc1[c], 0, 0, 0);
          acc1[c] = __builtin_amdgcn_mfma_f32_16x16x32_bf16(al, bh, acc1[c], 0, 0, 0);
        }
      }
    }
#pragma unroll
    for (int c = 0; c < 8; ++c) {
#pragma unroll
      for (int r = 0; r < 4; ++r) {
        const int row = (w << 4) + (lane >> 4) * 4 + r;
        const int col = c * 16 + (lane & 15);
        const int cc = (col >> 2) ^ (row & 7);
        hS[row * 128 + (cc << 2) + (col & 3)] = fmaxf(acc1[c][r], 0.f);
      }
    }
    __syncthreads();
    {
      const int arow = (w << 4) + (lane & 15);
      short8 a2h[4], a2l[4];
#pragma unroll
      for (int kc = 0; kc < 4; ++kc) {
        const int c8 = kc * 4 + (lane >> 4);
        const int base = arow * 128;
        const int cc0 = (2 * c8) ^ (arow & 7);
        const int cc1 = (2 * c8 + 1) ^ (arow & 7);
        const f32x4 q0 = *reinterpret_cast<const f32x4*>(&hS[base + (cc0 << 2)]);
        const f32x4 q1 = *reinterpret_cast<const f32x4*>(&hS[base + (cc1 << 2)]);
#pragma unroll
        for (int e = 0; e < 4; ++e) {
          unsigned short hi = rne_bf16(q0[e]);
          a2h[kc][e] = (short)hi;
          a2l[kc][e] = (short)rne_bf16(q0[e] - b2f(hi));
        }
#pragma unroll
        for (int e = 0; e < 4; ++e) {
          unsigned short hi = rne_bf16(q1[e]);
          a2h[kc][4 + e] = (short)hi;
          a2l[kc][4 + e] = (short)rne_bf16(q1[e] - b2f(hi));
        }
      }
      __syncthreads();
#pragma unroll
      for (int c = 0; c < 9; ++c) {
        f32x4 acc = (f32x4){0.f, 0.f, 0.f, 0.f};
        int bcol = c * 16 + (lane & 15);
        if (bcol > 128) bcol = 128;
#pragma unroll
        for (int kc = 0; kc < 4; ++kc) {
          const int c8 = kc * 4 + (lane >> 4);
          const int boff = bcol * 128 + ((c8 ^ (bcol & 7)) << 3);
          const short8 bh = *reinterpret_cast<const short8*>(&w2hS[boff]);
          const short8 bl = *reinterpret_cast<const short8*>(&w2lS[boff]);
          acc = __builtin_amdgcn_mfma_f32_16x16x32_bf16(a2h[kc], bh, acc, 0, 0, 0);
          acc = __builtin_amdgcn_mfma_f32_16x16x32_bf16(a2h[kc], bl, acc, 0, 0, 0);
          acc = __builtin_amdgcn_mfma_f32_16x16x32_bf16(a2l[kc], bh, acc, 0, 0, 0);
        }
        const int col = c * 16 + (lane & 15);
        if (col < 129) {
#pragma unroll
          for (int r = 0; r < 4; ++r) {
            const int lrow = (w << 4) + (lane >> 4) * 4 + r;
            outS[lrow * 129 + col] = acc[r];
          }
        }
      }
    }
    __syncthreads();
    {
      float* dst = Out + (size_t)row0 * 129;
      const f32x4* src = (const f32x4*)outS;
      for (int i = tid; i < 2064; i += 256)
        *reinterpret_cast<f32x4*>(dst + 4 * i) = src[i];
    }
    __syncthreads();
  }
}

extern "C" void kernel_launch(void* const* d_in, const int* in_sizes, int n_in,
                              void* d_out, int out_size, void* d_ws, size_t ws_size,
                              hipStream_t stream) {
  const float* X  = (const float*)d_in[0];
  const float* Tb = (const float*)d_in[1];
  const float* W1 = (const float*)d_in[2];
  const float* W2 = (const float*)d_in[3];
  float* Out = (float*)d_out;

  const int N = in_sizes[0] / 3;     // 1<<20
  const int nChunks = N / 64;        // 16384

  const size_t encBytes = (size_t)nChunks * 4096;       // 64 MiB bf16 A-fragments
  const size_t flagBytes = 4096 * sizeof(int);          // 16 KiB group flags
  if (N == (1 << 20) && ws_size >= encBytes + flagBytes) {
    unsigned short* encF = (unsigned short*)d_ws;
    int* flags = (int*)((char*)d_ws + encBytes);
    hipMemsetAsync(flags, 0, flagBytes, stream);
    fused_pc<<<512, 256, 0, stream>>>(X, Tb, W1, W2, encF, flags, Out);
  } else {
    int grid = nChunks < 1024 ? nChunks : 1024;
    fused_hashmlp<<<grid, 256, 0, stream>>>(X, Tb, W1, W2, Out, nChunks);
  }
}

// Round 13
// 625.381 us; speedup vs baseline: 1.0275x; 1.0275x over previous
//
#include <hip/hip_runtime.h>

typedef __attribute__((ext_vector_type(8))) short short8;
typedef __attribute__((ext_vector_type(4))) float f32x4;
typedef __attribute__((ext_vector_type(2))) unsigned long long u64x2;

#define TMASK  ((1u << 18) - 1u)
#define PRIME1 2654435761u
#define PRIME2 805459861u

// floor(16*SCALE^k), numpy SCALE = exp(ln(256)/16) rounds one ulp BELOW sqrt(2)
// -> even-k levels are 2^m - 1. Verified: rounds 7-12 PASS.
__constant__ float c_res[16] = {16.f, 22.f, 31.f, 45.f, 63.f, 90.f, 127.f, 181.f,
                                255.f, 362.f, 511.f, 724.f, 1023.f, 1448.f, 2047.f, 2896.f};

__device__ __forceinline__ unsigned short rne_bf16(float v) {
  unsigned u = __builtin_bit_cast(unsigned, v);
  return (unsigned short)((u + 0x7fffu + ((u >> 16) & 1u)) >> 16);
}
__device__ __forceinline__ float b2f(unsigned short h) {
  unsigned u = (unsigned)h << 16;
  return __builtin_bit_cast(float, u);
}

// one (point, level): 8-corner gather + smoothstep blend (verified rounds 7-12)
__device__ __forceinline__ float2 enc_level(float x0, float x1, float x2, int lvl,
                                            const float* __restrict__ Tb) {
  const float r = c_res[lvl];
  const float xs0 = x0 * r, xs1 = x1 * r, xs2 = x2 * r;   // plain f32 (jax semantics)
  const float f0 = floorf(xs0), f1 = floorf(xs1), f2 = floorf(xs2);
  const float t0 = xs0 - f0, t1 = xs1 - f1, t2 = xs2 - f2;
  const float w0 = t0 * t0 * (3.f - 2.f * t0);
  const float w1v = t1 * t1 * (3.f - 2.f * t1);
  const float w2v = t2 * t2 * (3.f - 2.f * t2);
  const unsigned cx0 = (unsigned)(int)f0;
  const unsigned hy0 = (unsigned)(int)f1 * PRIME1, hy1 = hy0 + PRIME1;
  const unsigned hz0 = (unsigned)(int)f2 * PRIME2, hz1 = hz0 + PRIME2;
  const float2* tab = reinterpret_cast<const float2*>(Tb) + ((size_t)lvl << 18);
  float a0 = 0.f, a1 = 0.f;
  if (!(cx0 & 1u)) {
    const float4* tab4 = reinterpret_cast<const float4*>(tab);
#pragma unroll
    for (int jk = 0; jk < 4; ++jk) {
      const unsigned hb = (cx0 ^ ((jk & 2) ? hy1 : hy0) ^ ((jk & 1) ? hz1 : hz0)) & TMASK;
      const float4 q = tab4[hb >> 1];
      float e0x, e0y, e1x, e1y;
      if (hb & 1) { e0x = q.z; e0y = q.w; e1x = q.x; e1y = q.y; }
      else        { e0x = q.x; e0y = q.y; e1x = q.z; e1y = q.w; }
      const float wy = (jk & 2) ? w1v : 1.f - w1v;
      const float wz = (jk & 1) ? w2v : 1.f - w2v;
      const float wt0 = ((1.f - w0) * wy) * wz;   // exact ((wx*wy)*wz) order
      const float wt1 = (w0 * wy) * wz;
      a0 = fmaf(e0x, wt0, a0); a1 = fmaf(e0y, wt0, a1);
      a0 = fmaf(e1x, wt1, a0); a1 = fmaf(e1y, wt1, a1);
    }
  } else {
#pragma unroll
    for (int c = 0; c < 8; ++c) {
      const unsigned hx = cx0 + (unsigned)((c >> 2) & 1);
      const unsigned hh = (hx ^ ((c & 2) ? hy1 : hy0) ^ ((c & 1) ? hz1 : hz0)) & TMASK;
      const float2 f = tab[hh];
      const float wt = (((c >> 2) & 1) ? w0 : 1.f - w0) *
                       (((c >> 1) & 1) ? w1v : 1.f - w1v) *
                       (((c & 1)) ? w2v : 1.f - w2v);
      a0 = fmaf(f.x, wt, a0);
      a1 = fmaf(f.y, wt, a1);
    }
  }
  return make_float2(a0, a1);
}

// ============ Fused persistent producer-consumer kernel (r12 structure) ============
// Handoff redesigned: encF[chunk][pair g][point] = 8B cell (levels {g,15-g} x 2
// feats). Producer wave writes 512B CONTIGUOUS (full lines -> no write-allocate
// amplification, was +260MB in r12). Consumer reads 2x8B system-scope loads per
// A-fragment; k-slot order is producer-grouped, W1 staged with the matching
// permutation (MFMA sum is k-permutation-invariant).
__global__ __launch_bounds__(256, 2) void fused_pc(
    const float* __restrict__ X, const float* __restrict__ Tb,
    const float* __restrict__ W1, const float* __restrict__ W2,
    unsigned short* __restrict__ encF, int* __restrict__ flags,
    float* __restrict__ Out) {
  __shared__ __align__(16) unsigned char lds[76800];
  __shared__ int ldsflag;
  unsigned short* w1S  = (unsigned short*)lds;             // [4 kgrp][128 col][8]
  float*          w1x  = (float*)(lds + 8192);             // [3][128]
  float*          xyzS = (float*)(lds + 9728);             // [64][4]
  unsigned short* w2hS = (unsigned short*)(lds + 10752);   // [16 c8][129][8]
  float*          hS   = (float*)(lds + 43776);            // [64][128]
  float*          outS = (float*)(lds + 43776);            // [64][129] overlay

  const int tid = threadIdx.x;
  const int lane = tid & 63, w = tid >> 6;
  const int b = blockIdx.x;
  const int g = b & 7;
  const int bslot = b >> 3;
  const int lvlA = g, lvlB = 15 - g;

  // ---- stage weights; W1 rows in producer-grouped k order ----
  // k-group s slot j -> level: j<2:2s, j<4:15-2s, j<6:2s+1, j>=6:14-2s; feat=j&1
  for (int idx = tid; idx < 32 * 128; idx += 256) {
    const int k = idx >> 7, col = idx & 127;
    const int s = k >> 3, j = k & 7;
    const int lvl = (j < 2) ? 2 * s : (j < 4) ? (15 - 2 * s)
                  : (j < 6) ? (2 * s + 1) : (14 - 2 * s);
    const int row = 3 + 2 * lvl + (j & 1);
    w1S[(s * 128 + col) * 8 + j] = rne_bf16(W1[row * 128 + col]);
  }
  for (int idx = tid; idx < 3 * 128; idx += 256) w1x[idx] = W1[idx];
  for (int idx = tid; idx < 128 * 129; idx += 256) {
    const int k = idx / 129, col = idx - k * 129;
    w2hS[((k >> 3) * 129 + col) * 8 + (k & 7)] = rne_bf16(W2[idx]);
  }
  __syncthreads();

  int nextI = 0;

  auto mlp_chunk = [&](int chunk) {
    // af: two 8B system-scope loads (coherent point; L2 of producer XCDs intact)
    const int s = lane >> 4;
    const int pl = (w << 4) | (lane & 15);
    const unsigned long long* e8 =
        (const unsigned long long*)encF + (size_t)chunk * 512 + pl;
    u64x2 av;
    av[0] = __hip_atomic_load(e8 + (size_t)(2 * s) * 64,
                              __ATOMIC_RELAXED, __HIP_MEMORY_SCOPE_SYSTEM);
    av[1] = __hip_atomic_load(e8 + (size_t)(2 * s + 1) * 64,
                              __ATOMIC_RELAXED, __HIP_MEMORY_SCOPE_SYSTEM);
    const short8 af = __builtin_bit_cast(short8, av);
    const int row0 = chunk << 6;
    if (tid < 192) xyzS[(tid / 3) * 4 + (tid % 3)] = X[(size_t)row0 * 3 + tid];
    __syncthreads();   // B1

    f32x4 acc1[8];
#pragma unroll
    for (int c = 0; c < 8; ++c) acc1[c] = (f32x4){0.f, 0.f, 0.f, 0.f};
#pragma unroll
    for (int c = 0; c < 8; ++c) {
      const short8 bb = *reinterpret_cast<const short8*>(
          &w1S[(s * 128 + c * 16 + (lane & 15)) * 8]);
      acc1[c] = __builtin_amdgcn_mfma_f32_16x16x32_bf16(af, bb, acc1[c], 0, 0, 0);
    }
#pragma unroll
    for (int r = 0; r < 4; ++r) {
      const int grow = (w << 4) + (lane >> 4) * 4 + r;
      const float xs0 = xyzS[grow * 4 + 0];
      const float xs1 = xyzS[grow * 4 + 1];
      const float xs2 = xyzS[grow * 4 + 2];
#pragma unroll
      for (int c = 0; c < 8; ++c) {
        const int col = c * 16 + (lane & 15);
        float v = acc1[c][r];
        v = fmaf(xs0, w1x[col], v);
        v = fmaf(xs1, w1x[128 + col], v);
        v = fmaf(xs2, w1x[256 + col], v);
        acc1[c][r] = v;
      }
    }
#pragma unroll
    for (int c = 0; c < 8; ++c) {
#pragma unroll
      for (int r = 0; r < 4; ++r) {
        const int row = (w << 4) + (lane >> 4) * 4 + r;
        const int col = c * 16 + (lane & 15);
        const int cc = (col >> 2) ^ (row & 7);
        hS[row * 128 + (cc << 2) + (col & 3)] = fmaxf(acc1[c][r], 0.f);
      }
    }
    __syncthreads();   // B2

    const int arow = (w << 4) + (lane & 15);
    short8 a2h[4], a2l[4];
#pragma unroll
    for (int kc = 0; kc < 4; ++kc) {
      const int c8 = kc * 4 + (lane >> 4);
      const int base = arow * 128;
      const int cc0 = (2 * c8) ^ (arow & 7);
      const int cc1 = (2 * c8 + 1) ^ (arow & 7);
      const f32x4 q0 = *reinterpret_cast<const f32x4*>(&hS[base + (cc0 << 2)]);
      const f32x4 q1 = *reinterpret_cast<const f32x4*>(&hS[base + (cc1 << 2)]);
#pragma unroll
      for (int e = 0; e < 4; ++e) {
        const unsigned short hi = rne_bf16(q0[e]);
        a2h[kc][e] = (short)hi;
        a2l[kc][e] = (short)rne_bf16(q0[e] - b2f(hi));
      }
#pragma unroll
      for (int e = 0; e < 4; ++e) {
        const unsigned short hi = rne_bf16(q1[e]);
        a2h[kc][4 + e] = (short)hi;
        a2l[kc][4 + e] = (short)rne_bf16(q1[e] - b2f(hi));
      }
    }
    __syncthreads();   // B3: h consumed, outS overlay safe

#pragma unroll
    for (int c = 0; c < 9; ++c) {
      f32x4 acc = (f32x4){0.f, 0.f, 0.f, 0.f};
      int bcol = c * 16 + (lane & 15);
      if (bcol > 128) bcol = 128;
#pragma unroll
      for (int kc = 0; kc < 4; ++kc) {
        const int c8 = kc * 4 + (lane >> 4);
        const short8 bh = *reinterpret_cast<const short8*>(&w2hS[(c8 * 129 + bcol) * 8]);
        acc = __builtin_amdgcn_mfma_f32_16x16x32_bf16(a2h[kc], bh, acc, 0, 0, 0);
        acc = __builtin_amdgcn_mfma_f32_16x16x32_bf16(a2l[kc], bh, acc, 0, 0, 0);
      }
      const int col = c * 16 + (lane & 15);
      if (col < 129) {
#pragma unroll
        for (int r = 0; r < 4; ++r) {
          const int lrow = (w << 4) + (lane >> 4) * 4 + r;
          outS[lrow * 129 + col] = acc[r];
        }
      }
    }
    __syncthreads();   // B4

    float* dst = Out + (size_t)row0 * 129;
    const f32x4* src = (const f32x4*)outS;
    for (int i = tid; i < 2064; i += 256)
      __builtin_nontemporal_store(src[i], reinterpret_cast<f32x4*>(dst + 4 * i));
  };

  // ---- main interleaved loop ----
  for (int t = 0; t < 64; ++t) {
    const int grp = bslot + t * 64;           // 0..4095
    {
      const int p = (grp << 8) + tid;
      const float x0 = X[p * 3 + 0];
      const float x1 = X[p * 3 + 1];
      const float x2 = X[p * 3 + 2];
      const float2 aA = enc_level(x0, x1, x2, lvlA, Tb);
      const float2 aB = enc_level(x0, x1, x2, lvlB, Tb);
      const unsigned long long cell =
          (unsigned long long)rne_bf16(aA.x)
          | ((unsigned long long)rne_bf16(aA.y) << 16)
          | ((unsigned long long)rne_bf16(aB.x) << 32)
          | ((unsigned long long)rne_bf16(aB.y) << 48);
      const int pl = p & 63, chunk = p >> 6;
      // wave writes 64 consecutive 8B cells = 512B contiguous (full lines)
      __hip_atomic_store((unsigned long long*)encF
                             + (size_t)chunk * 512 + (size_t)g * 64 + pl,
                         cell, __ATOMIC_RELAXED, __HIP_MEMORY_SCOPE_SYSTEM);
    }
    __syncthreads();   // drains vmcnt(0): stores at coherent point before flag
    if (tid == 0)
      __hip_atomic_fetch_add(&flags[grp], 1, __ATOMIC_RELAXED, __HIP_MEMORY_SCOPE_SYSTEM);

    // opportunistic MLP (non-blocking)
    while (nextI < 32) {
      const int c = b + (nextI << 9);
      if (tid == 0)
        ldsflag = __hip_atomic_load(&flags[c >> 2], __ATOMIC_RELAXED,
                                    __HIP_MEMORY_SCOPE_SYSTEM);
      __syncthreads();
      if (ldsflag != 8) break;   // block-uniform
      mlp_chunk(c);
      ++nextI;
    }
  }

  // ---- drain tail ----
  while (nextI < 32) {
    const int c = b + (nextI << 9);
    for (;;) {
      if (tid == 0)
        ldsflag = __hip_atomic_load(&flags[c >> 2], __ATOMIC_RELAXED,
                                    __HIP_MEMORY_SCOPE_SYSTEM);
      __syncthreads();
      if (ldsflag == 8) break;
      __builtin_amdgcn_s_sleep(32);
      __syncthreads();
    }
    mlp_chunk(c);
    ++nextI;
  }
}

// ================= Fallback (round-8 fused kernel, verified) =================
__global__ __launch_bounds__(256) void fused_hashmlp(
    const float* __restrict__ X, const float* __restrict__ Tb,
    const float* __restrict__ W1, const float* __restrict__ W2,
    float* __restrict__ Out, int nChunks) {
  __shared__ __align__(16) unsigned char lds[147968];
  unsigned short* w1hS = (unsigned short*)lds;
  unsigned short* w1lS = w1hS + 128 * 64;
  unsigned short* w2hS = (unsigned short*)(lds + 32768);
  unsigned short* w2lS = w2hS + 129 * 128;
  unsigned short* enchS = (unsigned short*)(lds + 98816);
  unsigned short* enclS = enchS + 64 * 64;
  float*          hS    = (float*)(lds + 115200);
  float*          outS  = (float*)(lds + 98816);

  const int tid = threadIdx.x;
  for (int idx = tid; idx < 128 * 64; idx += 256) {
    int k = idx >> 7, col = idx & 127;
    float v = 0.f;
    if (k < 35) { int r = (k < 32) ? (k + 3) : (k - 32); v = W1[r * 128 + col]; }
    unsigned short hi = rne_bf16(v);
    unsigned short lo = rne_bf16(v - b2f(hi));
    int a = col * 64 + (k ^ ((col & 7) << 3));
    w1hS[a] = hi; w1lS[a] = lo;
  }
  for (int idx = tid; idx < 129 * 128; idx += 256) {
    int k = idx / 129, col = idx - k * 129;
    float v = W2[k * 129 + col];
    unsigned short hi = rne_bf16(v);
    unsigned short lo = rne_bf16(v - b2f(hi));
    int a = col * 128 + (k ^ ((col & 7) << 3));
    w2hS[a] = hi; w2lS[a] = lo;
  }
  __syncthreads();

  const int p = tid >> 2, s = tid & 3, lane = tid & 63, w = tid >> 6;
  for (int chunk = blockIdx.x; chunk < nChunks; chunk += gridDim.x) {
    const int row0 = chunk * 64;
    {
      const int gp = row0 + p;
      const float x0 = X[gp * 3 + 0], x1 = X[gp * 3 + 1], x2 = X[gp * 3 + 2];
      short8 pkh, pkl;
#pragma unroll
      for (int li = 0; li < 4; ++li) {
        const int lvl = (s << 2) + li;
        const float2 a = enc_level(x0, x1, x2, lvl, Tb);
        unsigned short h0 = rne_bf16(a.x), h1 = rne_bf16(a.y);
        pkh[li * 2 + 0] = (short)h0; pkh[li * 2 + 1] = (short)h1;
        pkl[li * 2 + 0] = (short)rne_bf16(a.x - b2f(h0));
        pkl[li * 2 + 1] = (short)rne_bf16(a.y - b2f(h1));
      }
      const int coff = (s ^ (p & 7)) << 3;
      *reinterpret_cast<short8*>(&enchS[p * 64 + coff]) = pkh;
      *reinterpret_cast<short8*>(&enclS[p * 64 + coff]) = pkl;
      short8 zh, zl;
#pragma unroll
      for (int e = 0; e < 8; ++e) { zh[e] = 0; zl[e] = 0; }
      if (s == 0) {
        unsigned short hx0 = rne_bf16(x0), hx1 = rne_bf16(x1), hx2 = rne_bf16(x2);
        zh[0] = (short)hx0; zh[1] = (short)hx1; zh[2] = (short)hx2;
        zl[0] = (short)rne_bf16(x0 - b2f(hx0));
        zl[1] = (short)rne_bf16(x1 - b2f(hx1));
        zl[2] = (short)rne_bf16(x2 - b2f(hx2));
      }
      const int coff2 = ((4 + s) ^ (p & 7)) << 3;
      *reinterpret_cast<short8*>(&enchS[p * 64 + coff2]) = zh;
      *reinterpret_cast<short8*>(&enclS[p * 64 + coff2]) = zl;
    }
    __syncthreads();
    f32x4 acc1[8];
#pragma unroll
    for (int c = 0; c < 8; ++c) acc1[c] = (f32x4){0.f, 0.f, 0.f, 0.f};
    {
      const int arow = (w << 4) + (lane & 15);
#pragma unroll
      for (int kc = 0; kc < 2; ++kc) {
        const int c8 = kc * 4 + (lane >> 4);
        const int aoff = arow * 64 + ((c8 ^ (arow & 7)) << 3);
        const short8 ah = *reinterpret_cast<const short8*>(&enchS[aoff]);
        const short8 al = *reinterpret_cast<const short8*>(&enclS[aoff]);
#pragma unroll
        for (int c = 0; c < 8; ++c) {
          const int bcol = c * 16 + (lane & 15);
          const int boff = bcol * 64 + ((c8 ^ (bcol & 7)) << 3);
          const short8 bh = *reinterpret_cast<const short8*>(&w1hS[boff]);
          const short8 bl = *reinterpret_cast<const short8*>(&w1lS[boff]);
          acc1[c] = __builtin_amdgcn_mfma_f32_16x16x32_bf16(ah, bh, acc1[c], 0, 0, 0);
          acc1[c] = __builtin_amdgcn_mfma_f32_16x16x32_bf16(ah, bl, acc1[c], 0, 0, 0);
          acc1[c] = __builtin_amdgcn_mfma_f32_16x16x32_bf16(al, bh, acc1[c], 0, 0, 0);
        }
      }
    }
#pragma unroll
    for (int c = 0; c < 8; ++c) {
#pragma unroll
      for (int r = 0; r < 4; ++r) {
        const int row = (w << 4) + (lane >> 4) * 4 + r;
        const int col = c * 16 + (lane & 15);
        const int cc = (col >> 2) ^ (row & 7);
        hS[row * 128 + (cc << 2) + (col & 3)] = fmaxf(acc1[c][r], 0.f);
      }
    }
    __syncthreads();
    {
      const int arow = (w << 4) + (lane & 15);
      short8 a2h[4], a2l[4];
#pragma unroll
      for (int kc = 0; kc < 4; ++kc) {
        const int c8 = kc * 4 + (lane >> 4);
        const int base = arow * 128;
        const int cc0 = (2 * c8) ^ (arow & 7);
        const int cc1 = (2 * c8 + 1) ^ (arow & 7);
        const f32x4 q0 = *reinterpret_cast<const f32x4*>(&hS[base + (cc0 << 2)]);
        const f32x4 q1 = *reinterpret_cast<const f32x4*>(&hS[base + (cc1 << 2)]);
#pragma unroll
        for (int e = 0; e < 4; ++e) {
          unsigned short hi = rne_bf16(q0[e]);
          a2h[kc][e] = (short)hi;
          a2l[kc][e] = (short)rne_bf16(q0[e] - b2f(hi));
        }
#pragma unroll
        for (int e = 0; e < 4; ++e) {
          unsigned short hi = rne_bf16(q1[e]);
          a2h[kc][4 + e] = (short)hi;
          a2l[kc][4 + e] = (short)rne_bf16(q1[e] - b2f(hi));
        }
      }
      __syncthreads();
#pragma unroll
      for (int c = 0; c < 9; ++c) {
        f32x4 acc = (f32x4){0.f, 0.f, 0.f, 0.f};
        int bcol = c * 16 + (lane & 15);
        if (bcol > 128) bcol = 128;
#pragma unroll
        for (int kc = 0; kc < 4; ++kc) {
          const int c8 = kc * 4 + (lane >> 4);
          const int boff = bcol * 128 + ((c8 ^ (bcol & 7)) << 3);
          const short8 bh = *reinterpret_cast<const short8*>(&w2hS[boff]);
          const short8 bl = *reinterpret_cast<const short8*>(&w2lS[boff]);
          acc = __builtin_amdgcn_mfma_f32_16x16x32_bf16(a2h[kc], bh, acc, 0, 0, 0);
          acc = __builtin_amdgcn_mfma_f32_16x16x32_bf16(a2h[kc], bl, acc, 0, 0, 0);
          acc = __builtin_amdgcn_mfma_f32_16x16x32_bf16(a2l[kc], bh, acc, 0, 0, 0);
        }
        const int col = c * 16 + (lane & 15);
        if (col < 129) {
#pragma unroll
          for (int r = 0; r < 4; ++r) {
            const int lrow = (w << 4) + (lane >> 4) * 4 + r;
            outS[lrow * 129 + col] = acc[r];
          }
        }
      }
    }
    __syncthreads();
    {
      float* dst = Out + (size_t)row0 * 129;
      const f32x4* src = (const f32x4*)outS;
      for (int i = tid; i < 2064; i += 256)
        *reinterpret_cast<f32x4*>(dst + 4 * i) = src[i];
    }
    __syncthreads();
  }
}

extern "C" void kernel_launch(void* const* d_in, const int* in_sizes, int n_in,
                              void* d_out, int out_size, void* d_ws, size_t ws_size,
                              hipStream_t stream) {
  const float* X  = (const float*)d_in[0];
  const float* Tb = (const float*)d_in[1];
  const float* W1 = (const float*)d_in[2];
  const float* W2 = (const float*)d_in[3];
  float* Out = (float*)d_out;

  const int N = in_sizes[0] / 3;     // 1<<20
  const int nChunks = N / 64;        // 16384

  const size_t encBytes = (size_t)nChunks * 4096;       // 64 MiB bf16 handoff cells
  const size_t flagBytes = 4096 * sizeof(int);          // 16 KiB group flags
  if (N == (1 << 20) && ws_size >= encBytes + flagBytes) {
    unsigned short* encF = (unsigned short*)d_ws;
    int* flags = (int*)((char*)d_ws + encBytes);
    hipMemsetAsync(flags, 0, flagBytes, stream);
    fused_pc<<<512, 256, 0, stream>>>(X, Tb, W1, W2, encF, flags, Out);
  } else {
    int grid = nChunks < 1024 ? nChunks : 1024;
    fused_hashmlp<<<grid, 256, 0, stream>>>(X, Tb, W1, W2, Out, nChunks);
  }
}